// Round 1
// 629.878 us; speedup vs baseline: 1.0170x; 1.0170x over previous
//
#include <hip/hip_runtime.h>
#include <cstdint>
#include <cstddef>

// ---------------------------------------------------------------------------
// Types
// ---------------------------------------------------------------------------
typedef __attribute__((ext_vector_type(8))) short  short8;   // 8 x bf16 bits (4 VGPRs)
typedef __attribute__((ext_vector_type(4))) float  floatx4;  // MFMA acc
typedef __attribute__((ext_vector_type(4))) unsigned short ushort4v;

__device__ __forceinline__ unsigned short f2b(float f) {
  unsigned u = __builtin_bit_cast(unsigned, f);
  u = u + 0x7fffu + ((u >> 16) & 1u);   // RNE
  return (unsigned short)(u >> 16);
}

// async global->LDS, 16B per lane. LDS dest is wave-uniform base + lane*16.
__device__ __forceinline__ void gld_lds16(const void* g, void* l) {
  __builtin_amdgcn_global_load_lds(
      (const __attribute__((address_space(1))) unsigned int*)g,
      (__attribute__((address_space(3))) unsigned int*)l,
      16, 0, 0);
}

// ---------------------------------------------------------------------------
// fp32 -> bf16 cast (vectorized)
// ---------------------------------------------------------------------------
__global__ void __launch_bounds__(256) f2b_kernel(const float* __restrict__ in,
                                                  unsigned short* __restrict__ out,
                                                  int n4) {
  int i = blockIdx.x * 256 + threadIdx.x;
  if (i >= n4) return;
  floatx4 v = ((const floatx4*)in)[i];
  ushort4v o;
  o[0] = f2b(v[0]); o[1] = f2b(v[1]); o[2] = f2b(v[2]); o[3] = f2b(v[3]);
  ((ushort4v*)out)[i] = o;
}

// ---------------------------------------------------------------------------
// GEMM: C[M,N] = A[M,K] @ B[N,K]^T   (A,B bf16 row-major K-contiguous)
//
// 256xBN block tile (BN in {128,192}), BK=64, 8 waves (2M x 4N), 512 thr.
// Per wave: 128 x BN/4 output = 8 x NF fragments of 16x16 (NF = BN/64).
// 4 phases per K-tile (m-quadrant split), each phase:
//     ds_read A-frags -> raw s_barrier -> setprio(1) -> MFMA -> setprio(0)
//     -> raw s_barrier
// Phase 0 additionally reads all B-frags (held in regs for the whole tile)
// and issues the global_load_lds staging for tile t+1 into the other LDS
// buffer.  The ONLY vmcnt wait is a single vmcnt(0) at the end of phase 3 --
// it waits on loads issued ~3 phases earlier, so staging latency stays in
// flight across all intra-tile barriers (raw s_barrier has no drain).
//
// LDS swizzle (both-sides, rule 21): LDS[r][s] holds global octet s^(r&7)
// (octet = 16B = 8 bf16).  Staging pre-permutes the per-lane GLOBAL address
// (lds dest stays linear, required by global_load_lds); fragment ds_read
// XORs its k-octet with row&7.  Per 16-lane quad group the 16B reads spread
// across all 32 banks at 2 lanes/bank = conflict-free.
//
// Buffer parity is a compile-time constant (loop unrolled x2 via macro) so
// alias analysis can separate the two LDS halves.
//
// MODE: 1 = fp32 out, 2 = bf16 out + fused RoPE on cols<5120.
// Grid must be (8, N/BN); block swizzle assumes gridDim.x == 8, nwg%8==0.
// ---------------------------------------------------------------------------
template <int MODE, int BN>
__global__ void __launch_bounds__(512, 2)
gemm256(const unsigned short* __restrict__ A,
        const unsigned short* __restrict__ B,
        float* __restrict__ Cf,
        unsigned short* __restrict__ Cb,
        int K, int N,
        const float* __restrict__ fc,
        const float* __restrict__ fs) {
  constexpr int BM = 256, BK = 64;
  constexpr int NF  = BN / 64;   // n-frags per wave
  constexpr int WNC = BN / 4;    // per-wave col span
  constexpr int NB  = BN / 64;   // B staging instrs per wave (8 rows each)

  __shared__ __align__(16) unsigned short As[2][BM * BK];   // 64 KiB
  __shared__ __align__(16) unsigned short Bs[2][BN * BK];   // 32/48 KiB

  const int tid  = threadIdx.x;
  const int wave = tid >> 6, lane = tid & 63;
  const int quad = lane >> 4, l15 = lane & 15;
  const int wr = wave >> 2, wc = wave & 3;

  // XCD-chunked block swizzle: blocks resident on one XCD share A panels
  // (all 8) and a contiguous run of B panels -> L2 locality.
  int flat = blockIdx.y * 8 + blockIdx.x;
  const int cpx = (int)(gridDim.x * gridDim.y) >> 3;
  flat = (flat & 7) * cpx + (flat >> 3);
  const int m0 = (flat & 7) * BM;
  const int n0 = (flat >> 3) * BN;

  // ---- staging addresses (pre-swizzled global octet) ----
  const int srow = lane >> 3;            // row within 8-row block
  const int soct = (lane & 7) ^ srow;    // global octet for this lane's slot
  const unsigned short* pa[4];
  const unsigned short* pb[NB];
#pragma unroll
  for (int i = 0; i < 4; ++i)
    pa[i] = A + (size_t)(m0 + wave * 32 + i * 8 + srow) * K + soct * 8;
#pragma unroll
  for (int i = 0; i < NB; ++i)
    pb[i] = B + (size_t)(n0 + wave * (BN / 8) + i * 8 + srow) * K + soct * 8;

  // ---- fragment read offsets (ushort units); row&7 == l15&7 everywhere ----
  const int xr = l15 & 7;
  int aoff[2], boff[2];
#pragma unroll
  for (int ks = 0; ks < 2; ++ks) {
    const int sl = ((ks * 4 + quad) ^ xr) * 8;
    aoff[ks] = (wr * 128 + l15) * 64 + sl;
    boff[ks] = (wc * WNC + l15) * 64 + sl;
  }

  floatx4 acc[8][NF] = {};
  const int NT = K >> 6;

  // ---- prologue: stage tile 0 into buffer 0, publish ----
#pragma unroll
  for (int i = 0; i < 4; ++i)
    gld_lds16(pa[i], &As[0][(wave * 32 + i * 8) * 64]);
#pragma unroll
  for (int i = 0; i < NB; ++i)
    gld_lds16(pb[i], &Bs[0][(wave * (BN / 8) + i * 8) * 64]);
  asm volatile("s_waitcnt vmcnt(0)" ::: "memory");
  __builtin_amdgcn_s_barrier();
  __builtin_amdgcn_sched_barrier(0);

  int t = 0, kt = 0;

#define TILE_STEP(BUF)                                                         \
  do {                                                                         \
    /* phase 0: all B-frags + A-frags(mi=0,1); issue next-tile staging */      \
    short8 bfr[NF][2], afr[2][2];                                              \
    _Pragma("unroll") for (int n = 0; n < NF; ++n)                             \
      _Pragma("unroll") for (int ks = 0; ks < 2; ++ks)                         \
        bfr[n][ks] = *(const short8*)&Bs[BUF][boff[ks] + n * 1024];            \
    _Pragma("unroll") for (int mm = 0; mm < 2; ++mm)                           \
      _Pragma("unroll") for (int ks = 0; ks < 2; ++ks)                         \
        afr[mm][ks] = *(const short8*)&As[BUF][aoff[ks] + mm * 1024];          \
    if (t + 1 < NT) {                                                          \
      const int kn = kt + 64;                                                  \
      _Pragma("unroll") for (int i = 0; i < 4; ++i)                            \
        gld_lds16(pa[i] + kn, &As[1 - (BUF)][(wave * 32 + i * 8) * 64]);       \
      _Pragma("unroll") for (int i = 0; i < NB; ++i)                           \
        gld_lds16(pb[i] + kn, &Bs[1 - (BUF)][(wave * (BN / 8) + i * 8) * 64]); \
    }                                                                          \
    __builtin_amdgcn_s_barrier();                                              \
    __builtin_amdgcn_s_setprio(1);                                             \
    _Pragma("unroll") for (int mm = 0; mm < 2; ++mm)                           \
      _Pragma("unroll") for (int n = 0; n < NF; ++n)                           \
        _Pragma("unroll") for (int ks = 0; ks < 2; ++ks)                       \
          acc[mm][n] = __builtin_amdgcn_mfma_f32_16x16x32_bf16(                \
              afr[mm][ks], bfr[n][ks], acc[mm][n], 0, 0, 0);                   \
    __builtin_amdgcn_s_setprio(0);                                             \
    __builtin_amdgcn_s_barrier();                                              \
    /* phases 1..3: A-frags only; B stays in regs */                           \
    _Pragma("unroll") for (int p = 1; p < 4; ++p) {                            \
      short8 a2[2][2];                                                         \
      _Pragma("unroll") for (int mm = 0; mm < 2; ++mm)                         \
        _Pragma("unroll") for (int ks = 0; ks < 2; ++ks)                       \
          a2[mm][ks] =                                                         \
              *(const short8*)&As[BUF][aoff[ks] + (p * 2 + mm) * 1024];        \
      __builtin_amdgcn_s_barrier();                                            \
      __builtin_amdgcn_s_setprio(1);                                           \
      _Pragma("unroll") for (int mm = 0; mm < 2; ++mm)                         \
        _Pragma("unroll") for (int n = 0; n < NF; ++n)                         \
          _Pragma("unroll") for (int ks = 0; ks < 2; ++ks)                     \
            acc[p * 2 + mm][n] = __builtin_amdgcn_mfma_f32_16x16x32_bf16(      \
                a2[mm][ks], bfr[n][ks], acc[p * 2 + mm][n], 0, 0, 0);          \
      __builtin_amdgcn_s_setprio(0);                                           \
      if (p == 3) asm volatile("s_waitcnt vmcnt(0)" ::: "memory");             \
      __builtin_amdgcn_s_barrier();                                            \
    }                                                                          \
    __builtin_amdgcn_sched_barrier(0);                                         \
    kt += 64;                                                                  \
    ++t;                                                                       \
  } while (0)

  while (t < NT) {
    TILE_STEP(0);
    TILE_STEP(1);
  }
#undef TILE_STEP

  // ---- epilogue: C/D layout col = lane&15, row = quad*4 + reg ----
#pragma unroll
  for (int mi = 0; mi < 8; ++mi) {
#pragma unroll
    for (int n = 0; n < NF; ++n) {
      const int colb = n0 + wc * WNC + n * 16;   // wave-uniform
      const int col  = colb + l15;
      const bool rope = (MODE == 2) && (colb < 5120);
      const int pp = (col & 127) >> 1;
      const float sgn = (l15 & 1) ? 1.f : -1.f;
#pragma unroll
      for (int r = 0; r < 4; ++r) {
        const int row = m0 + wr * 128 + mi * 16 + quad * 4 + r;
        float v = acc[mi][n][r];
        if (rope) {
          const float partner = __shfl_xor(v, 1);
          const float c  = fc[row * 64 + pp];
          const float sn = fs[row * 64 + pp];
          v = v * c + partner * sn * sgn;
        }
        if (MODE == 1) Cf[(size_t)row * N + col] = v;
        else           Cb[(size_t)row * N + col] = f2b(v);
      }
    }
  }
}

// ---------------------------------------------------------------------------
// bf16 tiled transpose
// ---------------------------------------------------------------------------
__global__ void __launch_bounds__(256) transpose_bf16(const unsigned short* __restrict__ in,
                                                      unsigned short* __restrict__ out,
                                                      int R, int C, int in_stride) {
  __shared__ __align__(16) unsigned short tile[64][72];
  const int br = blockIdx.y * 64;
  const int bc = blockIdx.x * 64;
  const int tid = threadIdx.x;
  const int lr = tid >> 3;
  const int lc = (tid & 7) * 8;
#pragma unroll
  for (int it = 0; it < 2; ++it) {
    const int r = it * 32 + lr;
    *(short8*)&tile[r][lc] = *(const short8*)(in + (size_t)(br + r) * in_stride + bc + lc);
  }
  __syncthreads();
#pragma unroll
  for (int it = 0; it < 2; ++it) {
    const int c = it * 32 + lr;
    short8 v;
#pragma unroll
    for (int j = 0; j < 8; ++j) v[j] = (short)tile[lc + j][c];
    *(short8*)(out + (size_t)(bc + c) * R + br + lc) = v;
  }
}

// ---------------------------------------------------------------------------
// Flash attention v2 (causal, GQA 4:1). S=2048, D=128, 32 heads.
// 64-row q-tiles; block handles the PAIR (bx, 31-bx) -> exactly 33 k-tiles
// per block (perfect balance). 4 waves x 16 q-rows. K-tiles of 64 keys.
// Double-buffered K/V staging; prefetch issued right after the publishing
// barrier so global->LDS latency overlaps the whole compute of tile j.
// ---------------------------------------------------------------------------
#define SL2E 0.1275500406721347f   /* (1/sqrt(128)) * log2(e) */

__global__ void __launch_bounds__(256) flash_attn(const unsigned short* __restrict__ Q,  // (2048,6144)
                                                  const unsigned short* __restrict__ Kp, // (2048,6144)+off
                                                  const unsigned short* __restrict__ Vt, // (1024,2048)
                                                  unsigned short* __restrict__ O) {      // (2048,4096)
  constexpr int QS = 6144;
  const int bx  = blockIdx.x;      // 0..15 -> tiles bx and 31-bx
  const int h   = blockIdx.y;
  const int kvh = h >> 2;
  const int tid = threadIdx.x;
  const int wave = tid >> 6, lane = tid & 63;
  const int quad = lane >> 4, l15 = lane & 15;

  __shared__ __align__(16) unsigned short Ks[2][8192];   // 16 dc x 64 key x 8
  __shared__ __align__(16) unsigned short Vs[2][8192];   // 8 sc x 128 d x 8
  __shared__ __align__(16) unsigned short Ps[4][16 * 76];
  unsigned short* Pw = Ps[wave];

  const int i0 = wave * 4;
  const unsigned short* kbase = Kp + kvh * 128;
  const unsigned short* vbase[4];
  int vslot_sc[4];
#pragma unroll
  for (int ii = 0; ii < 4; ++ii) {
    const int i = i0 + ii;
    const int slot = i * 64 + lane;
    const int sc = slot >> 7, d = slot & 127;
    vbase[ii] = Vt + (size_t)(kvh * 128 + d) * 2048;
    vslot_sc[ii] = sc * 8;
  }

  for (int seg = 0; seg < 2; ++seg) {
    const int qt  = seg ? (31 - bx) : bx;
    const int q0  = qt * 64;
    const int qra = q0 + wave * 16;
    const int n   = qt + 1;

    short8 aq[4];
#pragma unroll
    for (int ks = 0; ks < 4; ++ks)
      aq[ks] = *(const short8*)(Q + (size_t)(qra + l15) * QS + h * 128 + ks * 32 + quad * 8);

    floatx4 oacc[8] = {};
    float mrow[4], lrow[4];
#pragma unroll
    for (int r = 0; r < 4; ++r) { mrow[r] = -1e30f; lrow[r] = 0.f; }

    {
      const int cc = 0;
#pragma unroll
      for (int ii = 0; ii < 4; ++ii) {
        const int i = i0 + ii;
        gld_lds16(kbase + (size_t)(cc + lane) * QS + i * 8, &Ks[0][i * 512]);
        gld_lds16(vbase[ii] + cc + vslot_sc[ii], &Vs[0][i * 512]);
      }
    }

    for (int j = 0; j < n; ++j) {
      __syncthreads();
      if (j + 1 < n) {
        const int cc = (j + 1) * 64;
        const int nb = (j + 1) & 1;
#pragma unroll
        for (int ii = 0; ii < 4; ++ii) {
          const int i = i0 + ii;
          gld_lds16(kbase + (size_t)(cc + lane) * QS + i * 8, &Ks[nb][i * 512]);
          gld_lds16(vbase[ii] + cc + vslot_sc[ii], &Vs[nb][i * 512]);
        }
      }
      const unsigned short* kb = Ks[j & 1];
      const unsigned short* vb = Vs[j & 1];
      const int c0 = j * 64;

      floatx4 sacc[4] = {};
#pragma unroll
      for (int ks = 0; ks < 4; ++ks) {
#pragma unroll
        for (int tn = 0; tn < 4; ++tn) {
          short8 bk = *(const short8*)&kb[((ks * 4 + quad) * 64 + tn * 16 + l15) * 8];
          sacc[tn] = __builtin_amdgcn_mfma_f32_16x16x32_bf16(aq[ks], bk, sacc[tn], 0, 0, 0);
        }
      }

      const bool needmask = (c0 + 63 > qra);
#pragma unroll
      for (int r = 0; r < 4; ++r) {
        const int rowg = qra + quad * 4 + r;
        float t0 = sacc[0][r] * SL2E, t1 = sacc[1][r] * SL2E;
        float t2 = sacc[2][r] * SL2E, t3 = sacc[3][r] * SL2E;
        if (needmask) {
          t0 = (c0 +  0 + l15 <= rowg) ? t0 : -1e30f;
          t1 = (c0 + 16 + l15 <= rowg) ? t1 : -1e30f;
          t2 = (c0 + 32 + l15 <= rowg) ? t2 : -1e30f;
          t3 = (c0 + 48 + l15 <= rowg) ? t3 : -1e30f;
        }
        float mx = fmaxf(fmaxf(t0, t1), fmaxf(t2, t3));
#pragma unroll
        for (int off = 1; off < 16; off <<= 1)
          mx = fmaxf(mx, __shfl_xor(mx, off, 16));
        const float mold = mrow[r];
        const float mn   = fmaxf(mold, mx);
        const float alpha = exp2f(mold - mn);
        float p0 = exp2f(t0 - mn), p1 = exp2f(t1 - mn);
        float p2 = exp2f(t2 - mn), p3 = exp2f(t3 - mn);
        sacc[0][r] = p0; sacc[1][r] = p1; sacc[2][r] = p2; sacc[3][r] = p3;
        float lsum = (p0 + p1) + (p2 + p3);
#pragma unroll
        for (int off = 1; off < 16; off <<= 1)
          lsum += __shfl_xor(lsum, off, 16);
        mrow[r] = mn;
        lrow[r] = lrow[r] * alpha + lsum;
#pragma unroll
        for (int tn = 0; tn < 8; ++tn) oacc[tn][r] *= alpha;
      }

#pragma unroll
      for (int tn = 0; tn < 4; ++tn)
#pragma unroll
        for (int r = 0; r < 4; ++r)
          Pw[(quad * 4 + r) * 76 + tn * 16 + l15] = f2b(sacc[tn][r]);

      short8 ap[2];
#pragma unroll
      for (int k2 = 0; k2 < 2; ++k2)
        ap[k2] = *(const short8*)&Pw[l15 * 76 + k2 * 32 + quad * 8];
#pragma unroll
      for (int k2 = 0; k2 < 2; ++k2) {
#pragma unroll
        for (int tn = 0; tn < 8; ++tn) {
          short8 bv = *(const short8*)&vb[((k2 * 4 + quad) * 128 + tn * 16 + l15) * 8];
          oacc[tn] = __builtin_amdgcn_mfma_f32_16x16x32_bf16(ap[k2], bv, oacc[tn], 0, 0, 0);
        }
      }
    }

#pragma unroll
    for (int r = 0; r < 4; ++r) {
      const float inv = 1.f / lrow[r];
      const int rowg = qra + quad * 4 + r;
#pragma unroll
      for (int tn = 0; tn < 8; ++tn)
        O[(size_t)rowg * 4096 + h * 128 + tn * 16 + l15] = f2b(oacc[tn][r] * inv);
    }
    __syncthreads();
  }
}

// ---------------------------------------------------------------------------
// Host launcher
// ---------------------------------------------------------------------------
extern "C" void kernel_launch(void* const* d_in, const int* in_sizes, int n_in,
                              void* d_out, int out_size, void* d_ws, size_t ws_size,
                              hipStream_t stream) {
  const float* x  = (const float*)d_in[0];
  const float* wq = (const float*)d_in[1];
  const float* wk = (const float*)d_in[2];
  const float* wv = (const float*)d_in[3];
  const float* wo = (const float*)d_in[4];
  const float* fc = (const float*)d_in[7];
  const float* fs = (const float*)d_in[8];
  float* out = (float*)d_out;

  char* ws = (char*)d_ws;
  unsigned short* xb    = (unsigned short*)(ws + 0);          // x bf16       16 MB
  unsigned short* wqkvb = (unsigned short*)(ws + 16777216);   // wq|wk|wv     48 MB
  unsigned short* wob   = (unsigned short*)(ws + 67108864);   // wo bf16      32 MB
  unsigned short* qkv   = (unsigned short*)(ws + 100663296);  // (2048,6144)  24 MB
  unsigned short* vt    = (unsigned short*)(ws + 125829120);  // (1024,2048)   4 MB
  unsigned short* ob    = (unsigned short*)(ws + 130023424);  // (2048,4096)  16 MB
  unsigned short* wkb = wqkvb + (size_t)4096 * 4096;
  unsigned short* wvb = wkb + (size_t)1024 * 4096;

  f2b_kernel<<<8192,  256, 0, stream>>>(x,  xb,    2097152);
  f2b_kernel<<<16384, 256, 0, stream>>>(wq, wqkvb, 4194304);
  f2b_kernel<<<4096,  256, 0, stream>>>(wk, wkb,   1048576);
  f2b_kernel<<<4096,  256, 0, stream>>>(wv, wvb,   1048576);
  f2b_kernel<<<16384, 256, 0, stream>>>(wo, wob,   4194304);

  // QKV projection with fused RoPE on Q|K columns: (2048,6144) = xb @ wqkv^T
  // BM=256, BN=192 -> grid (8,32) = 256 blocks = 1 per CU.
  gemm256<2, 192><<<dim3(8, 32), 512, 0, stream>>>(xb, wqkvb, nullptr, qkv,
                                                   4096, 6144, fc, fs);

  // V^T: (2048,1024) slice at col 5120 -> (1024,2048)
  transpose_bf16<<<dim3(16, 32), 256, 0, stream>>>(qkv + 5120, vt, 2048, 1024, 6144);

  // flash attention -> O (2048,4096) bf16
  flash_attn<<<dim3(16, 32), 256, 0, stream>>>(qkv, qkv + 4096, vt, ob);

  // output projection: O @ wo^T -> fp32 d_out
  // BM=256, BN=128 -> grid (8,32) = 256 blocks = 1 per CU.
  gemm256<1, 128><<<dim3(8, 32), 512, 0, stream>>>(ob, wob, out, nullptr,
                                                   4096, 4096, nullptr, nullptr);
}

// Round 2
// 584.743 us; speedup vs baseline: 1.0955x; 1.0772x over previous
//
#include <hip/hip_runtime.h>
#include <cstdint>
#include <cstddef>

// ---------------------------------------------------------------------------
// Types
// ---------------------------------------------------------------------------
typedef __attribute__((ext_vector_type(8))) short  short8;   // 8 x bf16 bits (4 VGPRs)
typedef __attribute__((ext_vector_type(4))) float  floatx4;  // MFMA acc
typedef __attribute__((ext_vector_type(4))) unsigned short ushort4v;

__device__ __forceinline__ unsigned short f2b(float f) {
  unsigned u = __builtin_bit_cast(unsigned, f);
  u = u + 0x7fffu + ((u >> 16) & 1u);   // RNE
  return (unsigned short)(u >> 16);
}

// async global->LDS, 16B per lane. LDS dest is wave-uniform base + lane*16.
__device__ __forceinline__ void gld_lds16(const void* g, void* l) {
  __builtin_amdgcn_global_load_lds(
      (const __attribute__((address_space(1))) unsigned int*)g,
      (__attribute__((address_space(3))) unsigned int*)l,
      16, 0, 0);
}

// inline-asm ds_read_b128: invisible to the compiler's waitcnt-insertion pass,
// so it does NOT trigger conservative vmcnt waits against in-flight
// global_load_lds DMA (the round-1 per-phase stall).  Caller owns the
// s_waitcnt lgkmcnt + sched_barrier(0) fence (rule 18).
__device__ __forceinline__ short8 ds_read_b128v(const unsigned short* p) {
  short8 r;
  asm volatile("ds_read_b128 %0, %1"
               : "=v"(r)
               : "v"((const __attribute__((address_space(3))) unsigned short*)p));
  return r;
}

#define LGKM0_FENCE()                                        \
  do {                                                       \
    asm volatile("s_waitcnt lgkmcnt(0)" ::: "memory");       \
    __builtin_amdgcn_sched_barrier(0);                       \
  } while (0)

// ---------------------------------------------------------------------------
// fp32 -> bf16 cast (vectorized)
// ---------------------------------------------------------------------------
__global__ void __launch_bounds__(256) f2b_kernel(const float* __restrict__ in,
                                                  unsigned short* __restrict__ out,
                                                  int n4) {
  int i = blockIdx.x * 256 + threadIdx.x;
  if (i >= n4) return;
  floatx4 v = ((const floatx4*)in)[i];
  ushort4v o;
  o[0] = f2b(v[0]); o[1] = f2b(v[1]); o[2] = f2b(v[2]); o[3] = f2b(v[3]);
  ((ushort4v*)out)[i] = o;
}

// ---------------------------------------------------------------------------
// GEMM: C[M,N] = A[M,K] @ B[N,K]^T   (A,B bf16 row-major K-contiguous)
//
// 256xBN block tile (BN in {128,192}), BK=64, 8 waves (2M x 4N), 512 thr.
// 4 phases per K-tile; per phase:
//     asm ds_read A-frags -> raw s_barrier -> lgkmcnt(0)+sched_barrier
//     -> setprio(1) -> MFMA -> setprio(0) -> raw s_barrier
// Phase 0 additionally reads all B-frags (held in regs for the whole tile)
// and issues next-tile global_load_lds staging into the other LDS buffer.
// Single s_waitcnt vmcnt(0) per K-tile at end of phase 3 (covers loads
// issued ~3 phases earlier); raw s_barrier never drains counters.
//
// LDS swizzle (both-sides, rule 21): LDS[r][s] holds global octet s^(r&7).
// Staging pre-permutes the per-lane GLOBAL address (LDS dest stays linear);
// fragment ds_read XORs its k-octet with row&7.  Conflict-free (measured 0).
//
// MODE: 1 = fp32 out, 2 = bf16 out + fused RoPE on cols<5120.
// Grid must be (8, N/BN); block swizzle assumes gridDim.x == 8.
// ---------------------------------------------------------------------------
template <int MODE, int BN>
__global__ void __launch_bounds__(512, 2)
gemm256(const unsigned short* __restrict__ A,
        const unsigned short* __restrict__ B,
        float* __restrict__ Cf,
        unsigned short* __restrict__ Cb,
        int K, int N,
        const float* __restrict__ fc,
        const float* __restrict__ fs) {
  constexpr int BM = 256, BK = 64;
  constexpr int NF  = BN / 64;   // n-frags per wave
  constexpr int WNC = BN / 4;    // per-wave col span
  constexpr int NB  = BN / 64;   // B staging instrs per wave (8 rows each)

  __shared__ __align__(16) unsigned short As[2][BM * BK];   // 64 KiB
  __shared__ __align__(16) unsigned short Bs[2][BN * BK];   // 32/48 KiB

  const int tid  = threadIdx.x;
  const int wave = tid >> 6, lane = tid & 63;
  const int quad = lane >> 4, l15 = lane & 15;
  const int wr = wave >> 2, wc = wave & 3;

  // XCD-chunked block swizzle: blocks resident on one XCD share all 8 A
  // panels and a contiguous run of B panels -> L2 locality.
  int flat = blockIdx.y * 8 + blockIdx.x;
  const int cpx = (int)(gridDim.x * gridDim.y) >> 3;
  flat = (flat & 7) * cpx + (flat >> 3);
  const int m0 = (flat & 7) * BM;
  const int n0 = (flat >> 3) * BN;

  // ---- staging addresses (pre-swizzled global octet) ----
  const int srow = lane >> 3;            // row within 8-row block
  const int soct = (lane & 7) ^ srow;    // global octet for this lane's slot
  const unsigned short* pa[4];
  const unsigned short* pb[NB];
#pragma unroll
  for (int i = 0; i < 4; ++i)
    pa[i] = A + (size_t)(m0 + wave * 32 + i * 8 + srow) * K + soct * 8;
#pragma unroll
  for (int i = 0; i < NB; ++i)
    pb[i] = B + (size_t)(n0 + wave * (BN / 8) + i * 8 + srow) * K + soct * 8;

  // ---- fragment read offsets (ushort units); row&7 == l15&7 everywhere ----
  const int xr = l15 & 7;
  int aoff[2], boff[2];
#pragma unroll
  for (int ks = 0; ks < 2; ++ks) {
    const int sl = ((ks * 4 + quad) ^ xr) * 8;
    aoff[ks] = (wr * 128 + l15) * 64 + sl;
    boff[ks] = (wc * WNC + l15) * 64 + sl;
  }

  floatx4 acc[8][NF] = {};
  const int NT = K >> 6;

  // ---- prologue: stage tile 0 into buffer 0, publish ----
#pragma unroll
  for (int i = 0; i < 4; ++i)
    gld_lds16(pa[i], &As[0][(wave * 32 + i * 8) * 64]);
#pragma unroll
  for (int i = 0; i < NB; ++i)
    gld_lds16(pb[i], &Bs[0][(wave * (BN / 8) + i * 8) * 64]);
  asm volatile("s_waitcnt vmcnt(0)" ::: "memory");
  __builtin_amdgcn_s_barrier();
  __builtin_amdgcn_sched_barrier(0);

  int t = 0, kt = 0;

#define TILE_STEP(BUF)                                                         \
  do {                                                                         \
    /* phase 0: all B-frags + A-frags(mi=0,1); issue next-tile staging */      \
    short8 bfr[NF][2], afr[2][2];                                              \
    _Pragma("unroll") for (int n = 0; n < NF; ++n)                             \
      _Pragma("unroll") for (int ks = 0; ks < 2; ++ks)                         \
        bfr[n][ks] = ds_read_b128v(&Bs[BUF][boff[ks] + n * 1024]);             \
    _Pragma("unroll") for (int mm = 0; mm < 2; ++mm)                           \
      _Pragma("unroll") for (int ks = 0; ks < 2; ++ks)                         \
        afr[mm][ks] = ds_read_b128v(&As[BUF][aoff[ks] + mm * 1024]);           \
    if (t + 1 < NT) {                                                          \
      const int kn = kt + 64;                                                  \
      _Pragma("unroll") for (int i = 0; i < 4; ++i)                            \
        gld_lds16(pa[i] + kn, &As[1 - (BUF)][(wave * 32 + i * 8) * 64]);       \
      _Pragma("unroll") for (int i = 0; i < NB; ++i)                           \
        gld_lds16(pb[i] + kn, &Bs[1 - (BUF)][(wave * (BN / 8) + i * 8) * 64]); \
    }                                                                          \
    __builtin_amdgcn_s_barrier();                                              \
    LGKM0_FENCE();                                                             \
    __builtin_amdgcn_s_setprio(1);                                             \
    _Pragma("unroll") for (int mm = 0; mm < 2; ++mm)                           \
      _Pragma("unroll") for (int n = 0; n < NF; ++n)                           \
        _Pragma("unroll") for (int ks = 0; ks < 2; ++ks)                       \
          acc[mm][n] = __builtin_amdgcn_mfma_f32_16x16x32_bf16(                \
              afr[mm][ks], bfr[n][ks], acc[mm][n], 0, 0, 0);                   \
    __builtin_amdgcn_s_setprio(0);                                             \
    __builtin_amdgcn_s_barrier();                                              \
    /* phases 1..3: A-frags only; B stays in regs */                           \
    _Pragma("unroll") for (int p = 1; p < 4; ++p) {                            \
      short8 a2[2][2];                                                         \
      _Pragma("unroll") for (int mm = 0; mm < 2; ++mm)                         \
        _Pragma("unroll") for (int ks = 0; ks < 2; ++ks)                       \
          a2[mm][ks] =                                                         \
              ds_read_b128v(&As[BUF][aoff[ks] + (p * 2 + mm) * 1024]);         \
      __builtin_amdgcn_s_barrier();                                            \
      LGKM0_FENCE();                                                           \
      __builtin_amdgcn_s_setprio(1);                                           \
      _Pragma("unroll") for (int mm = 0; mm < 2; ++mm)                         \
        _Pragma("unroll") for (int n = 0; n < NF; ++n)                         \
          _Pragma("unroll") for (int ks = 0; ks < 2; ++ks)                     \
            acc[p * 2 + mm][n] = __builtin_amdgcn_mfma_f32_16x16x32_bf16(      \
                a2[mm][ks], bfr[n][ks], acc[p * 2 + mm][n], 0, 0, 0);          \
      __builtin_amdgcn_s_setprio(0);                                           \
      if (p == 3) asm volatile("s_waitcnt vmcnt(0)" ::: "memory");             \
      __builtin_amdgcn_s_barrier();                                            \
    }                                                                          \
    __builtin_amdgcn_sched_barrier(0);                                         \
    kt += 64;                                                                  \
    ++t;                                                                       \
  } while (0)

  while (t < NT) {
    TILE_STEP(0);
    TILE_STEP(1);
  }
#undef TILE_STEP

  // ---- epilogue: C/D layout col = lane&15, row = quad*4 + reg ----
#pragma unroll
  for (int mi = 0; mi < 8; ++mi) {
#pragma unroll
    for (int n = 0; n < NF; ++n) {
      const int colb = n0 + wc * WNC + n * 16;   // wave-uniform
      const int col  = colb + l15;
      const bool rope = (MODE == 2) && (colb < 5120);
      const int pp = (col & 127) >> 1;
      const float sgn = (l15 & 1) ? 1.f : -1.f;
#pragma unroll
      for (int r = 0; r < 4; ++r) {
        const int row = m0 + wr * 128 + mi * 16 + quad * 4 + r;
        float v = acc[mi][n][r];
        if (rope) {
          const float partner = __shfl_xor(v, 1);
          const float c  = fc[row * 64 + pp];
          const float sn = fs[row * 64 + pp];
          v = v * c + partner * sn * sgn;
        }
        if (MODE == 1) Cf[(size_t)row * N + col] = v;
        else           Cb[(size_t)row * N + col] = f2b(v);
      }
    }
  }
}

// ---------------------------------------------------------------------------
// bf16 tiled transpose
// ---------------------------------------------------------------------------
__global__ void __launch_bounds__(256) transpose_bf16(const unsigned short* __restrict__ in,
                                                      unsigned short* __restrict__ out,
                                                      int R, int C, int in_stride) {
  __shared__ __align__(16) unsigned short tile[64][72];
  const int br = blockIdx.y * 64;
  const int bc = blockIdx.x * 64;
  const int tid = threadIdx.x;
  const int lr = tid >> 3;
  const int lc = (tid & 7) * 8;
#pragma unroll
  for (int it = 0; it < 2; ++it) {
    const int r = it * 32 + lr;
    *(short8*)&tile[r][lc] = *(const short8*)(in + (size_t)(br + r) * in_stride + bc + lc);
  }
  __syncthreads();
#pragma unroll
  for (int it = 0; it < 2; ++it) {
    const int c = it * 32 + lr;
    short8 v;
#pragma unroll
    for (int j = 0; j < 8; ++j) v[j] = (short)tile[lc + j][c];
    *(short8*)(out + (size_t)(bc + c) * R + br + lc) = v;
  }
}

// ---------------------------------------------------------------------------
// Flash attention v2 (causal, GQA 4:1). S=2048, D=128, 32 heads.
// 64-row q-tiles; block handles the PAIR (bx, 31-bx) -> exactly 33 k-tiles
// per block (perfect balance). 4 waves x 16 q-rows. K-tiles of 64 keys.
// Double-buffered K/V staging; prefetch issued right after the publishing
// barrier so global->LDS latency overlaps the whole compute of tile j.
// ---------------------------------------------------------------------------
#define SL2E 0.1275500406721347f   /* (1/sqrt(128)) * log2(e) */

__global__ void __launch_bounds__(256) flash_attn(const unsigned short* __restrict__ Q,  // (2048,6144)
                                                  const unsigned short* __restrict__ Kp, // (2048,6144)+off
                                                  const unsigned short* __restrict__ Vt, // (1024,2048)
                                                  unsigned short* __restrict__ O) {      // (2048,4096)
  constexpr int QS = 6144;
  const int bx  = blockIdx.x;      // 0..15 -> tiles bx and 31-bx
  const int h   = blockIdx.y;
  const int kvh = h >> 2;
  const int tid = threadIdx.x;
  const int wave = tid >> 6, lane = tid & 63;
  const int quad = lane >> 4, l15 = lane & 15;

  __shared__ __align__(16) unsigned short Ks[2][8192];   // 16 dc x 64 key x 8
  __shared__ __align__(16) unsigned short Vs[2][8192];   // 8 sc x 128 d x 8
  __shared__ __align__(16) unsigned short Ps[4][16 * 76];
  unsigned short* Pw = Ps[wave];

  const int i0 = wave * 4;
  const unsigned short* kbase = Kp + kvh * 128;
  const unsigned short* vbase[4];
  int vslot_sc[4];
#pragma unroll
  for (int ii = 0; ii < 4; ++ii) {
    const int i = i0 + ii;
    const int slot = i * 64 + lane;
    const int sc = slot >> 7, d = slot & 127;
    vbase[ii] = Vt + (size_t)(kvh * 128 + d) * 2048;
    vslot_sc[ii] = sc * 8;
  }

  for (int seg = 0; seg < 2; ++seg) {
    const int qt  = seg ? (31 - bx) : bx;
    const int q0  = qt * 64;
    const int qra = q0 + wave * 16;
    const int n   = qt + 1;

    short8 aq[4];
#pragma unroll
    for (int ks = 0; ks < 4; ++ks)
      aq[ks] = *(const short8*)(Q + (size_t)(qra + l15) * QS + h * 128 + ks * 32 + quad * 8);

    floatx4 oacc[8] = {};
    float mrow[4], lrow[4];
#pragma unroll
    for (int r = 0; r < 4; ++r) { mrow[r] = -1e30f; lrow[r] = 0.f; }

    {
      const int cc = 0;
#pragma unroll
      for (int ii = 0; ii < 4; ++ii) {
        const int i = i0 + ii;
        gld_lds16(kbase + (size_t)(cc + lane) * QS + i * 8, &Ks[0][i * 512]);
        gld_lds16(vbase[ii] + cc + vslot_sc[ii], &Vs[0][i * 512]);
      }
    }

    for (int j = 0; j < n; ++j) {
      __syncthreads();
      if (j + 1 < n) {
        const int cc = (j + 1) * 64;
        const int nb = (j + 1) & 1;
#pragma unroll
        for (int ii = 0; ii < 4; ++ii) {
          const int i = i0 + ii;
          gld_lds16(kbase + (size_t)(cc + lane) * QS + i * 8, &Ks[nb][i * 512]);
          gld_lds16(vbase[ii] + cc + vslot_sc[ii], &Vs[nb][i * 512]);
        }
      }
      const unsigned short* kb = Ks[j & 1];
      const unsigned short* vb = Vs[j & 1];
      const int c0 = j * 64;

      floatx4 sacc[4] = {};
#pragma unroll
      for (int ks = 0; ks < 4; ++ks) {
#pragma unroll
        for (int tn = 0; tn < 4; ++tn) {
          short8 bk = *(const short8*)&kb[((ks * 4 + quad) * 64 + tn * 16 + l15) * 8];
          sacc[tn] = __builtin_amdgcn_mfma_f32_16x16x32_bf16(aq[ks], bk, sacc[tn], 0, 0, 0);
        }
      }

      const bool needmask = (c0 + 63 > qra);
#pragma unroll
      for (int r = 0; r < 4; ++r) {
        const int rowg = qra + quad * 4 + r;
        float t0 = sacc[0][r] * SL2E, t1 = sacc[1][r] * SL2E;
        float t2 = sacc[2][r] * SL2E, t3 = sacc[3][r] * SL2E;
        if (needmask) {
          t0 = (c0 +  0 + l15 <= rowg) ? t0 : -1e30f;
          t1 = (c0 + 16 + l15 <= rowg) ? t1 : -1e30f;
          t2 = (c0 + 32 + l15 <= rowg) ? t2 : -1e30f;
          t3 = (c0 + 48 + l15 <= rowg) ? t3 : -1e30f;
        }
        float mx = fmaxf(fmaxf(t0, t1), fmaxf(t2, t3));
#pragma unroll
        for (int off = 1; off < 16; off <<= 1)
          mx = fmaxf(mx, __shfl_xor(mx, off, 16));
        const float mold = mrow[r];
        const float mn   = fmaxf(mold, mx);
        const float alpha = exp2f(mold - mn);
        float p0 = exp2f(t0 - mn), p1 = exp2f(t1 - mn);
        float p2 = exp2f(t2 - mn), p3 = exp2f(t3 - mn);
        sacc[0][r] = p0; sacc[1][r] = p1; sacc[2][r] = p2; sacc[3][r] = p3;
        float lsum = (p0 + p1) + (p2 + p3);
#pragma unroll
        for (int off = 1; off < 16; off <<= 1)
          lsum += __shfl_xor(lsum, off, 16);
        mrow[r] = mn;
        lrow[r] = lrow[r] * alpha + lsum;
#pragma unroll
        for (int tn = 0; tn < 8; ++tn) oacc[tn][r] *= alpha;
      }

#pragma unroll
      for (int tn = 0; tn < 4; ++tn)
#pragma unroll
        for (int r = 0; r < 4; ++r)
          Pw[(quad * 4 + r) * 76 + tn * 16 + l15] = f2b(sacc[tn][r]);

      short8 ap[2];
#pragma unroll
      for (int k2 = 0; k2 < 2; ++k2)
        ap[k2] = *(const short8*)&Pw[l15 * 76 + k2 * 32 + quad * 8];
#pragma unroll
      for (int k2 = 0; k2 < 2; ++k2) {
#pragma unroll
        for (int tn = 0; tn < 8; ++tn) {
          short8 bv = *(const short8*)&vb[((k2 * 4 + quad) * 128 + tn * 16 + l15) * 8];
          oacc[tn] = __builtin_amdgcn_mfma_f32_16x16x32_bf16(ap[k2], bv, oacc[tn], 0, 0, 0);
        }
      }
    }

#pragma unroll
    for (int r = 0; r < 4; ++r) {
      const float inv = 1.f / lrow[r];
      const int rowg = qra + quad * 4 + r;
#pragma unroll
      for (int tn = 0; tn < 8; ++tn)
        O[(size_t)rowg * 4096 + h * 128 + tn * 16 + l15] = f2b(oacc[tn][r] * inv);
    }
    __syncthreads();
  }
}

// ---------------------------------------------------------------------------
// Host launcher
// ---------------------------------------------------------------------------
extern "C" void kernel_launch(void* const* d_in, const int* in_sizes, int n_in,
                              void* d_out, int out_size, void* d_ws, size_t ws_size,
                              hipStream_t stream) {
  const float* x  = (const float*)d_in[0];
  const float* wq = (const float*)d_in[1];
  const float* wk = (const float*)d_in[2];
  const float* wv = (const float*)d_in[3];
  const float* wo = (const float*)d_in[4];
  const float* fc = (const float*)d_in[7];
  const float* fs = (const float*)d_in[8];
  float* out = (float*)d_out;

  char* ws = (char*)d_ws;
  unsigned short* xb    = (unsigned short*)(ws + 0);          // x bf16       16 MB
  unsigned short* wqkvb = (unsigned short*)(ws + 16777216);   // wq|wk|wv     48 MB
  unsigned short* wob   = (unsigned short*)(ws + 67108864);   // wo bf16      32 MB
  unsigned short* qkv   = (unsigned short*)(ws + 100663296);  // (2048,6144)  24 MB
  unsigned short* vt    = (unsigned short*)(ws + 125829120);  // (1024,2048)   4 MB
  unsigned short* ob    = (unsigned short*)(ws + 130023424);  // (2048,4096)  16 MB
  unsigned short* wkb = wqkvb + (size_t)4096 * 4096;
  unsigned short* wvb = wkb + (size_t)1024 * 4096;

  f2b_kernel<<<8192,  256, 0, stream>>>(x,  xb,    2097152);
  f2b_kernel<<<16384, 256, 0, stream>>>(wq, wqkvb, 4194304);
  f2b_kernel<<<4096,  256, 0, stream>>>(wk, wkb,   1048576);
  f2b_kernel<<<4096,  256, 0, stream>>>(wv, wvb,   1048576);
  f2b_kernel<<<16384, 256, 0, stream>>>(wo, wob,   4194304);

  // QKV projection with fused RoPE on Q|K columns: (2048,6144) = xb @ wqkv^T
  // BM=256, BN=192 -> grid (8,32) = 256 blocks = 1 per CU.
  gemm256<2, 192><<<dim3(8, 32), 512, 0, stream>>>(xb, wqkvb, nullptr, qkv,
                                                   4096, 6144, fc, fs);

  // V^T: (2048,1024) slice at col 5120 -> (1024,2048)
  transpose_bf16<<<dim3(16, 32), 256, 0, stream>>>(qkv + 5120, vt, 2048, 1024, 6144);

  // flash attention -> O (2048,4096) bf16
  flash_attn<<<dim3(16, 32), 256, 0, stream>>>(qkv, qkv + 4096, vt, ob);

  // output projection: O @ wo^T -> fp32 d_out
  // BM=256, BN=128 -> grid (8,32) = 256 blocks = 1 per CU.
  gemm256<1, 128><<<dim3(8, 32), 512, 0, stream>>>(ob, wob, out, nullptr,
                                                   4096, 4096, nullptr, nullptr);
}

// Round 4
// 549.311 us; speedup vs baseline: 1.1662x; 1.0645x over previous
//
#include <hip/hip_runtime.h>
#include <cstdint>
#include <cstddef>

// ---------------------------------------------------------------------------
// Types
// ---------------------------------------------------------------------------
typedef __attribute__((ext_vector_type(8))) short  short8;   // 8 x bf16 bits (4 VGPRs)
typedef __attribute__((ext_vector_type(4))) float  floatx4;  // MFMA acc
typedef __attribute__((ext_vector_type(4))) unsigned short ushort4v;

__device__ __forceinline__ unsigned short f2b(float f) {
  unsigned u = __builtin_bit_cast(unsigned, f);
  u = u + 0x7fffu + ((u >> 16) & 1u);   // RNE
  return (unsigned short)(u >> 16);
}

// async global->LDS, 16B per lane. LDS dest is wave-uniform base + lane*16.
__device__ __forceinline__ void gld_lds16(const void* g, void* l) {
  __builtin_amdgcn_global_load_lds(
      (const __attribute__((address_space(1))) unsigned int*)g,
      (__attribute__((address_space(3))) unsigned int*)l,
      16, 0, 0);
}

// inline-asm LDS ops: invisible to the compiler's waitcnt-insertion pass, so
// they do NOT trigger conservative vmcnt waits against in-flight
// global_load_lds DMA.  Caller owns s_waitcnt lgkmcnt + sched_barrier(0)
// (rule 18: mandatory fence, or hipcc hoists register-only MFMAs past it).
__device__ __forceinline__ short8 ds_read_b128v(const unsigned short* p) {
  short8 r;
  asm volatile("ds_read_b128 %0, %1"
               : "=v"(r)
               : "v"((const __attribute__((address_space(3))) unsigned short*)p));
  return r;
}
__device__ __forceinline__ void ds_write_b16v(unsigned short* p, unsigned short v) {
  asm volatile("ds_write_b16 %0, %1"
               :: "v"((__attribute__((address_space(3))) unsigned short*)p),
                  "v"((unsigned)v)
               : "memory");
}

#define LGKM_FENCE(N)                                        \
  do {                                                       \
    asm volatile("s_waitcnt lgkmcnt(" #N ")" ::: "memory");  \
    __builtin_amdgcn_sched_barrier(0);                       \
  } while (0)
#define LGKM0_FENCE() LGKM_FENCE(0)

// ---------------------------------------------------------------------------
// fp32 -> bf16 cast (vectorized)
// ---------------------------------------------------------------------------
__global__ void __launch_bounds__(256) f2b_kernel(const float* __restrict__ in,
                                                  unsigned short* __restrict__ out,
                                                  int n4) {
  int i = blockIdx.x * 256 + threadIdx.x;
  if (i >= n4) return;
  floatx4 v = ((const floatx4*)in)[i];
  ushort4v o;
  o[0] = f2b(v[0]); o[1] = f2b(v[1]); o[2] = f2b(v[2]); o[3] = f2b(v[3]);
  ((ushort4v*)out)[i] = o;
}

// ---------------------------------------------------------------------------
// GEMM: C[M,N] = A[M,K] @ B[N,K]^T   (A,B bf16 row-major K-contiguous)
// 256xBN tile, BK=64, 8 waves, 4 phases/K-tile, asm ds_read + counted fences,
// single vmcnt(0)/tile.  See round-2 notes.  UNCHANGED.
// ---------------------------------------------------------------------------
template <int MODE, int BN>
__global__ void __launch_bounds__(512, 2)
gemm256(const unsigned short* __restrict__ A,
        const unsigned short* __restrict__ B,
        float* __restrict__ Cf,
        unsigned short* __restrict__ Cb,
        int K, int N,
        const float* __restrict__ fc,
        const float* __restrict__ fs) {
  constexpr int BM = 256, BK = 64;
  constexpr int NF  = BN / 64;   // n-frags per wave
  constexpr int WNC = BN / 4;    // per-wave col span
  constexpr int NB  = BN / 64;   // B staging instrs per wave (8 rows each)

  __shared__ __align__(16) unsigned short As[2][BM * BK];   // 64 KiB
  __shared__ __align__(16) unsigned short Bs[2][BN * BK];   // 32/48 KiB

  const int tid  = threadIdx.x;
  const int wave = tid >> 6, lane = tid & 63;
  const int quad = lane >> 4, l15 = lane & 15;
  const int wr = wave >> 2, wc = wave & 3;

  int flat = blockIdx.y * 8 + blockIdx.x;
  const int cpx = (int)(gridDim.x * gridDim.y) >> 3;
  flat = (flat & 7) * cpx + (flat >> 3);
  const int m0 = (flat & 7) * BM;
  const int n0 = (flat >> 3) * BN;

  const int srow = lane >> 3;            // row within 8-row block
  const int soct = (lane & 7) ^ srow;    // global octet for this lane's slot
  const unsigned short* pa[4];
  const unsigned short* pb[NB];
#pragma unroll
  for (int i = 0; i < 4; ++i)
    pa[i] = A + (size_t)(m0 + wave * 32 + i * 8 + srow) * K + soct * 8;
#pragma unroll
  for (int i = 0; i < NB; ++i)
    pb[i] = B + (size_t)(n0 + wave * (BN / 8) + i * 8 + srow) * K + soct * 8;

  const int xr = l15 & 7;
  int aoff[2], boff[2];
#pragma unroll
  for (int ks = 0; ks < 2; ++ks) {
    const int sl = ((ks * 4 + quad) ^ xr) * 8;
    aoff[ks] = (wr * 128 + l15) * 64 + sl;
    boff[ks] = (wc * WNC + l15) * 64 + sl;
  }

  floatx4 acc[8][NF] = {};
  const int NT = K >> 6;

#pragma unroll
  for (int i = 0; i < 4; ++i)
    gld_lds16(pa[i], &As[0][(wave * 32 + i * 8) * 64]);
#pragma unroll
  for (int i = 0; i < NB; ++i)
    gld_lds16(pb[i], &Bs[0][(wave * (BN / 8) + i * 8) * 64]);
  asm volatile("s_waitcnt vmcnt(0)" ::: "memory");
  __builtin_amdgcn_s_barrier();
  __builtin_amdgcn_sched_barrier(0);

  int t = 0, kt = 0;

#define TILE_STEP(BUF)                                                         \
  do {                                                                         \
    short8 bfr[NF][2], afr[2][2];                                              \
    _Pragma("unroll") for (int n = 0; n < NF; ++n)                             \
      _Pragma("unroll") for (int ks = 0; ks < 2; ++ks)                         \
        bfr[n][ks] = ds_read_b128v(&Bs[BUF][boff[ks] + n * 1024]);             \
    _Pragma("unroll") for (int mm = 0; mm < 2; ++mm)                           \
      _Pragma("unroll") for (int ks = 0; ks < 2; ++ks)                         \
        afr[mm][ks] = ds_read_b128v(&As[BUF][aoff[ks] + mm * 1024]);           \
    if (t + 1 < NT) {                                                          \
      const int kn = kt + 64;                                                  \
      _Pragma("unroll") for (int i = 0; i < 4; ++i)                            \
        gld_lds16(pa[i] + kn, &As[1 - (BUF)][(wave * 32 + i * 8) * 64]);       \
      _Pragma("unroll") for (int i = 0; i < NB; ++i)                           \
        gld_lds16(pb[i] + kn, &Bs[1 - (BUF)][(wave * (BN / 8) + i * 8) * 64]); \
    }                                                                          \
    __builtin_amdgcn_s_barrier();                                              \
    LGKM0_FENCE();                                                             \
    __builtin_amdgcn_s_setprio(1);                                             \
    _Pragma("unroll") for (int mm = 0; mm < 2; ++mm)                           \
      _Pragma("unroll") for (int n = 0; n < NF; ++n)                           \
        _Pragma("unroll") for (int ks = 0; ks < 2; ++ks)                       \
          acc[mm][n] = __builtin_amdgcn_mfma_f32_16x16x32_bf16(                \
              afr[mm][ks], bfr[n][ks], acc[mm][n], 0, 0, 0);                   \
    __builtin_amdgcn_s_setprio(0);                                             \
    __builtin_amdgcn_s_barrier();                                              \
    _Pragma("unroll") for (int p = 1; p < 4; ++p) {                            \
      short8 a2[2][2];                                                         \
      _Pragma("unroll") for (int mm = 0; mm < 2; ++mm)                         \
        _Pragma("unroll") for (int ks = 0; ks < 2; ++ks)                       \
          a2[mm][ks] =                                                         \
              ds_read_b128v(&As[BUF][aoff[ks] + (p * 2 + mm) * 1024]);         \
      __builtin_amdgcn_s_barrier();                                            \
      LGKM0_FENCE();                                                           \
      __builtin_amdgcn_s_setprio(1);                                           \
      _Pragma("unroll") for (int mm = 0; mm < 2; ++mm)                         \
        _Pragma("unroll") for (int n = 0; n < NF; ++n)                         \
          _Pragma("unroll") for (int ks = 0; ks < 2; ++ks)                     \
            acc[p * 2 + mm][n] = __builtin_amdgcn_mfma_f32_16x16x32_bf16(      \
                a2[mm][ks], bfr[n][ks], acc[p * 2 + mm][n], 0, 0, 0);          \
      __builtin_amdgcn_s_setprio(0);                                           \
      if (p == 3) asm volatile("s_waitcnt vmcnt(0)" ::: "memory");             \
      __builtin_amdgcn_s_barrier();                                            \
    }                                                                          \
    __builtin_amdgcn_sched_barrier(0);                                         \
    kt += 64;                                                                  \
    ++t;                                                                       \
  } while (0)

  while (t < NT) {
    TILE_STEP(0);
    TILE_STEP(1);
  }
#undef TILE_STEP

#pragma unroll
  for (int mi = 0; mi < 8; ++mi) {
#pragma unroll
    for (int n = 0; n < NF; ++n) {
      const int colb = n0 + wc * WNC + n * 16;   // wave-uniform
      const int col  = colb + l15;
      const bool rope = (MODE == 2) && (colb < 5120);
      const int pp = (col & 127) >> 1;
      const float sgn = (l15 & 1) ? 1.f : -1.f;
#pragma unroll
      for (int r = 0; r < 4; ++r) {
        const int row = m0 + wr * 128 + mi * 16 + quad * 4 + r;
        float v = acc[mi][n][r];
        if (rope) {
          const float partner = __shfl_xor(v, 1);
          const float c  = fc[row * 64 + pp];
          const float sn = fs[row * 64 + pp];
          v = v * c + partner * sn * sgn;
        }
        if (MODE == 1) Cf[(size_t)row * N + col] = v;
        else           Cb[(size_t)row * N + col] = f2b(v);
      }
    }
  }
}

// ---------------------------------------------------------------------------
// bf16 tiled transpose
// ---------------------------------------------------------------------------
__global__ void __launch_bounds__(256) transpose_bf16(const unsigned short* __restrict__ in,
                                                      unsigned short* __restrict__ out,
                                                      int R, int C, int in_stride) {
  __shared__ __align__(16) unsigned short tile[64][72];
  const int br = blockIdx.y * 64;
  const int bc = blockIdx.x * 64;
  const int tid = threadIdx.x;
  const int lr = tid >> 3;
  const int lc = (tid & 7) * 8;
#pragma unroll
  for (int it = 0; it < 2; ++it) {
    const int r = it * 32 + lr;
    *(short8*)&tile[r][lc] = *(const short8*)(in + (size_t)(br + r) * in_stride + bc + lc);
  }
  __syncthreads();
#pragma unroll
  for (int it = 0; it < 2; ++it) {
    const int c = it * 32 + lr;
    short8 v;
#pragma unroll
    for (int j = 0; j < 8; ++j) v[j] = (short)tile[lc + j][c];
    *(short8*)(out + (size_t)(bc + c) * R + br + lc) = v;
  }
}

// ---------------------------------------------------------------------------
// Flash attention v2 (causal, GQA 4:1). S=2048, D=128, 32 heads.
// 64-row q-tiles; block handles the PAIR (bx, 31-bx) -> exactly 33 k-tiles.
// 4 waves x 16 q-rows.  Double-buffered K/V, COALESCED staging:
//   K LDS [key 64][d-oct ^ (key&7)]  (instr = 4 rows x 256B contiguous)
//   V LDS [d 128][key-oct ^ (d&7)]   (instr = 8 rows x 128B contiguous)
// (both-sides swizzle, rule 21: pre-swizzled GLOBAL octet, linear LDS dest,
//  XOR-swizzled asm ds_read -> 2 lanes/bank = conflict-free).
// All k-loop LDS ops are inline asm + counted lgkm fences (no compiler
// vmcnt serialization); tile-top = explicit vmcnt(0) + raw s_barrier.
// Prefetch issued AFTER softmax so the compiler-visible shuffles run with
// zero outstanding DMA; PV covers the coalesced L2 latency.
// ---------------------------------------------------------------------------
#define SL2E 0.1275500406721347f   /* (1/sqrt(128)) * log2(e) */

__global__ void __launch_bounds__(256) flash_attn(const unsigned short* __restrict__ Q,  // (2048,6144)
                                                  const unsigned short* __restrict__ Kp, // (2048,6144)+off
                                                  const unsigned short* __restrict__ Vt, // (1024,2048)
                                                  unsigned short* __restrict__ O) {      // (2048,4096)
  constexpr int QS = 6144;
  const int bx  = blockIdx.x;      // 0..15 -> tiles bx and 31-bx
  const int h   = blockIdx.y;
  const int kvh = h >> 2;
  const int tid = threadIdx.x;
  const int wave = tid >> 6, lane = tid & 63;
  const int quad = lane >> 4, l15 = lane & 15;
  const int xr8 = l15 & 7;

  __shared__ __align__(16) unsigned short Ks[2][8192];   // [key 64][128 d swz]
  __shared__ __align__(16) unsigned short Vs[2][8192];   // [d 128][64 key swz]
  __shared__ __align__(16) unsigned short Ps[4][16 * 88];
  unsigned short* Pw = Ps[wave];

  // ---- coalesced staging sources (pre-swizzled global octet) ----
  const unsigned short* kp4[4];   // instr ii: keys k0..k0+3, k0 = wave*16+ii*4
  const unsigned short* vp4[4];   // instr ii: d-rows d0..d0+7, d0 = wave*32+ii*8
#pragma unroll
  for (int ii = 0; ii < 4; ++ii) {
    const int k0   = wave * 16 + ii * 4;
    const int krow = k0 + (lane >> 4);
    const int goct = (lane & 15) ^ (krow & 7);
    kp4[ii] = Kp + kvh * 128 + (size_t)krow * QS + goct * 8;
    const int d0   = wave * 32 + ii * 8;
    const int drow = d0 + (lane >> 3);
    const int voct = (lane & 7) ^ ((lane >> 3) & 7);
    vp4[ii] = Vt + (size_t)(kvh * 128 + drow) * 2048 + voct * 8;
  }

  for (int seg = 0; seg < 2; ++seg) {
    const int qt  = seg ? (31 - bx) : bx;
    const int qra = qt * 64 + wave * 16;
    const int n   = qt + 1;

    short8 aq[4];
#pragma unroll
    for (int ks = 0; ks < 4; ++ks)
      aq[ks] = *(const short8*)(Q + (size_t)(qra + l15) * QS + h * 128 + ks * 32 + quad * 8);

    floatx4 oacc[8] = {};
    float mrow[4], lrow[4];
#pragma unroll
    for (int r = 0; r < 4; ++r) { mrow[r] = -1e30f; lrow[r] = 0.f; }

    // prologue: stage tile 0 -> buffer 0
#pragma unroll
    for (int ii = 0; ii < 4; ++ii) {
      gld_lds16(kp4[ii], &Ks[0][wave * 2048 + ii * 512]);
      gld_lds16(vp4[ii], &Vs[0][wave * 2048 + ii * 512]);
    }

    for (int j = 0; j < n; ++j) {
      // publish staged tile: per-wave DMA drain, raw barrier (no lgkm drain)
      asm volatile("s_waitcnt vmcnt(0)" ::: "memory");
      __builtin_amdgcn_s_barrier();
      __builtin_amdgcn_sched_barrier(0);
      const unsigned short* kb = Ks[j & 1];
      const unsigned short* vb = Vs[j & 1];
      const int c0 = j * 64;

      // ---- QK^T: 2-deep pipelined asm ds_reads + MFMA ----
      floatx4 sacc[4] = {};
      {
        short8 bkA[4], bkB[4];
#pragma unroll
        for (int tn = 0; tn < 4; ++tn)
          bkA[tn] = ds_read_b128v(&kb[(tn * 16 + l15) * 128 + ((quad ^ xr8) * 8)]);
#pragma unroll
        for (int tn = 0; tn < 4; ++tn)
          bkB[tn] = ds_read_b128v(&kb[(tn * 16 + l15) * 128 + (((4 + quad) ^ xr8) * 8)]);
        LGKM_FENCE(4);
        __builtin_amdgcn_s_setprio(1);
#pragma unroll
        for (int tn = 0; tn < 4; ++tn)
          sacc[tn] = __builtin_amdgcn_mfma_f32_16x16x32_bf16(aq[0], bkA[tn], sacc[tn], 0, 0, 0);
        __builtin_amdgcn_s_setprio(0);
#pragma unroll
        for (int tn = 0; tn < 4; ++tn)
          bkA[tn] = ds_read_b128v(&kb[(tn * 16 + l15) * 128 + (((8 + quad) ^ xr8) * 8)]);
        LGKM_FENCE(4);
        __builtin_amdgcn_s_setprio(1);
#pragma unroll
        for (int tn = 0; tn < 4; ++tn)
          sacc[tn] = __builtin_amdgcn_mfma_f32_16x16x32_bf16(aq[1], bkB[tn], sacc[tn], 0, 0, 0);
        __builtin_amdgcn_s_setprio(0);
#pragma unroll
        for (int tn = 0; tn < 4; ++tn)
          bkB[tn] = ds_read_b128v(&kb[(tn * 16 + l15) * 128 + (((12 + quad) ^ xr8) * 8)]);
        LGKM_FENCE(4);
        __builtin_amdgcn_s_setprio(1);
#pragma unroll
        for (int tn = 0; tn < 4; ++tn)
          sacc[tn] = __builtin_amdgcn_mfma_f32_16x16x32_bf16(aq[2], bkA[tn], sacc[tn], 0, 0, 0);
        __builtin_amdgcn_s_setprio(0);
        LGKM_FENCE(0);
        __builtin_amdgcn_s_setprio(1);
#pragma unroll
        for (int tn = 0; tn < 4; ++tn)
          sacc[tn] = __builtin_amdgcn_mfma_f32_16x16x32_bf16(aq[3], bkB[tn], sacc[tn], 0, 0, 0);
        __builtin_amdgcn_s_setprio(0);
      }

      // ---- online softmax (no outstanding DMA here -> shuffles are clean) ----
      const bool needmask = (c0 + 63 > qra);
#pragma unroll
      for (int r = 0; r < 4; ++r) {
        const int rowg = qra + quad * 4 + r;
        float t0 = sacc[0][r] * SL2E, t1 = sacc[1][r] * SL2E;
        float t2 = sacc[2][r] * SL2E, t3 = sacc[3][r] * SL2E;
        if (needmask) {
          t0 = (c0 +  0 + l15 <= rowg) ? t0 : -1e30f;
          t1 = (c0 + 16 + l15 <= rowg) ? t1 : -1e30f;
          t2 = (c0 + 32 + l15 <= rowg) ? t2 : -1e30f;
          t3 = (c0 + 48 + l15 <= rowg) ? t3 : -1e30f;
        }
        float mx = fmaxf(fmaxf(t0, t1), fmaxf(t2, t3));
#pragma unroll
        for (int off = 1; off < 16; off <<= 1)
          mx = fmaxf(mx, __shfl_xor(mx, off, 16));
        const float mold = mrow[r];
        const float mn   = fmaxf(mold, mx);
        const float alpha = exp2f(mold - mn);
        float p0 = exp2f(t0 - mn), p1 = exp2f(t1 - mn);
        float p2 = exp2f(t2 - mn), p3 = exp2f(t3 - mn);
        sacc[0][r] = p0; sacc[1][r] = p1; sacc[2][r] = p2; sacc[3][r] = p3;
        float lsum = (p0 + p1) + (p2 + p3);
#pragma unroll
        for (int off = 1; off < 16; off <<= 1)
          lsum += __shfl_xor(lsum, off, 16);
        mrow[r] = mn;
        lrow[r] = lrow[r] * alpha + lsum;
#pragma unroll
        for (int tn = 0; tn < 8; ++tn) oacc[tn][r] *= alpha;
      }

      // ---- prefetch next tile (latency covered by P-write + PV) ----
      if (j + 1 < n) {
        const int cc = (j + 1) * 64;
        const int nb = (j + 1) & 1;
#pragma unroll
        for (int ii = 0; ii < 4; ++ii) {
          gld_lds16(kp4[ii] + (size_t)cc * QS, &Ks[nb][wave * 2048 + ii * 512]);
          gld_lds16(vp4[ii] + cc, &Vs[nb][wave * 2048 + ii * 512]);
        }
      }

      // ---- P -> LDS (bf16, asm), transpose read, PV ----
#pragma unroll
      for (int tn = 0; tn < 4; ++tn)
#pragma unroll
        for (int r = 0; r < 4; ++r)
          ds_write_b16v(&Pw[(quad * 4 + r) * 88 + tn * 16 + l15], f2b(sacc[tn][r]));
      short8 ap0 = ds_read_b128v(&Pw[l15 * 88 + quad * 8]);
      short8 ap1 = ds_read_b128v(&Pw[l15 * 88 + 32 + quad * 8]);
      short8 bv0[8], bv1[8];
#pragma unroll
      for (int tn = 0; tn < 8; ++tn)
        bv0[tn] = ds_read_b128v(&vb[(tn * 16 + l15) * 64 + ((quad ^ xr8) * 8)]);
#pragma unroll
      for (int tn = 0; tn < 8; ++tn)
        bv1[tn] = ds_read_b128v(&vb[(tn * 16 + l15) * 64 + (((4 + quad) ^ xr8) * 8)]);
      LGKM_FENCE(8);   // in-order: P-writes, ap0/ap1, bv0 complete; bv1 pending
      __builtin_amdgcn_s_setprio(1);
#pragma unroll
      for (int tn = 0; tn < 8; ++tn)
        oacc[tn] = __builtin_amdgcn_mfma_f32_16x16x32_bf16(ap0, bv0[tn], oacc[tn], 0, 0, 0);
      __builtin_amdgcn_s_setprio(0);
      LGKM_FENCE(0);
      __builtin_amdgcn_s_setprio(1);
#pragma unroll
      for (int tn = 0; tn < 8; ++tn)
        oacc[tn] = __builtin_amdgcn_mfma_f32_16x16x32_bf16(ap1, bv1[tn], oacc[tn], 0, 0, 0);
      __builtin_amdgcn_s_setprio(0);
    }

#pragma unroll
    for (int r = 0; r < 4; ++r) {
      const float inv = 1.f / lrow[r];
      const int rowg = qra + quad * 4 + r;
#pragma unroll
      for (int tn = 0; tn < 8; ++tn)
        O[(size_t)rowg * 4096 + h * 128 + tn * 16 + l15] = f2b(oacc[tn][r] * inv);
    }
    __syncthreads();   // full drain: safe buffer reuse across segs
  }
}

// ---------------------------------------------------------------------------
// Host launcher
// ---------------------------------------------------------------------------
extern "C" void kernel_launch(void* const* d_in, const int* in_sizes, int n_in,
                              void* d_out, int out_size, void* d_ws, size_t ws_size,
                              hipStream_t stream) {
  const float* x  = (const float*)d_in[0];
  const float* wq = (const float*)d_in[1];
  const float* wk = (const float*)d_in[2];
  const float* wv = (const float*)d_in[3];
  const float* wo = (const float*)d_in[4];
  const float* fc = (const float*)d_in[7];
  const float* fs = (const float*)d_in[8];
  float* out = (float*)d_out;

  char* ws = (char*)d_ws;
  unsigned short* xb    = (unsigned short*)(ws + 0);          // x bf16       16 MB
  unsigned short* wqkvb = (unsigned short*)(ws + 16777216);   // wq|wk|wv     48 MB
  unsigned short* wob   = (unsigned short*)(ws + 67108864);   // wo bf16      32 MB
  unsigned short* qkv   = (unsigned short*)(ws + 100663296);  // (2048,6144)  24 MB
  unsigned short* vt    = (unsigned short*)(ws + 125829120);  // (1024,2048)   4 MB
  unsigned short* ob    = (unsigned short*)(ws + 130023424);  // (2048,4096)  16 MB
  unsigned short* wkb = wqkvb + (size_t)4096 * 4096;
  unsigned short* wvb = wkb + (size_t)1024 * 4096;

  f2b_kernel<<<8192,  256, 0, stream>>>(x,  xb,    2097152);
  f2b_kernel<<<16384, 256, 0, stream>>>(wq, wqkvb, 4194304);
  f2b_kernel<<<4096,  256, 0, stream>>>(wk, wkb,   1048576);
  f2b_kernel<<<4096,  256, 0, stream>>>(wv, wvb,   1048576);
  f2b_kernel<<<16384, 256, 0, stream>>>(wo, wob,   4194304);

  // QKV projection with fused RoPE on Q|K columns: (2048,6144) = xb @ wqkv^T
  gemm256<2, 192><<<dim3(8, 32), 512, 0, stream>>>(xb, wqkvb, nullptr, qkv,
                                                   4096, 6144, fc, fs);

  // V^T: (2048,1024) slice at col 5120 -> (1024,2048)
  transpose_bf16<<<dim3(16, 32), 256, 0, stream>>>(qkv + 5120, vt, 2048, 1024, 6144);

  // flash attention -> O (2048,4096) bf16
  flash_attn<<<dim3(16, 32), 256, 0, stream>>>(qkv, qkv + 4096, vt, ob);

  // output projection: O @ wo^T -> fp32 d_out
  gemm256<1, 128><<<dim3(8, 32), 512, 0, stream>>>(ob, wob, out, nullptr,
                                                   4096, 4096, nullptr, nullptr);
}

// Round 5
// 538.465 us; speedup vs baseline: 1.1897x; 1.0201x over previous
//
#include <hip/hip_runtime.h>
#include <cstdint>
#include <cstddef>

// ---------------------------------------------------------------------------
// Types
// ---------------------------------------------------------------------------
typedef __attribute__((ext_vector_type(8))) short  short8;   // 8 x bf16 bits (4 VGPRs)
typedef __attribute__((ext_vector_type(4))) float  floatx4;  // MFMA acc
typedef __attribute__((ext_vector_type(4))) unsigned short ushort4v;

__device__ __forceinline__ unsigned short f2b(float f) {
  unsigned u = __builtin_bit_cast(unsigned, f);
  u = u + 0x7fffu + ((u >> 16) & 1u);   // RNE
  return (unsigned short)(u >> 16);
}

// async global->LDS, 16B per lane. LDS dest is wave-uniform base + lane*16.
__device__ __forceinline__ void gld_lds16(const void* g, void* l) {
  __builtin_amdgcn_global_load_lds(
      (const __attribute__((address_space(1))) unsigned int*)g,
      (__attribute__((address_space(3))) unsigned int*)l,
      16, 0, 0);
}

// inline-asm LDS ops: invisible to the compiler's waitcnt-insertion pass, so
// they do NOT trigger conservative vmcnt waits against in-flight
// global_load_lds DMA.  Caller owns s_waitcnt lgkmcnt + sched_barrier(0)
// (rule 18: mandatory fence, or hipcc hoists register-only MFMAs past it).
__device__ __forceinline__ short8 ds_read_b128v(const unsigned short* p) {
  short8 r;
  asm volatile("ds_read_b128 %0, %1"
               : "=v"(r)
               : "v"((const __attribute__((address_space(3))) unsigned short*)p));
  return r;
}
__device__ __forceinline__ void ds_write_b16v(unsigned short* p, unsigned short v) {
  asm volatile("ds_write_b16 %0, %1"
               :: "v"((__attribute__((address_space(3))) unsigned short*)p),
                  "v"((unsigned)v)
               : "memory");
}

#define LGKM_FENCE(N)                                        \
  do {                                                       \
    asm volatile("s_waitcnt lgkmcnt(" #N ")" ::: "memory");  \
    __builtin_amdgcn_sched_barrier(0);                       \
  } while (0)
#define LGKM0_FENCE() LGKM_FENCE(0)

// ---------------------------------------------------------------------------
// fp32 -> bf16 cast (vectorized)
// ---------------------------------------------------------------------------
__global__ void __launch_bounds__(256) f2b_kernel(const float* __restrict__ in,
                                                  unsigned short* __restrict__ out,
                                                  int n4) {
  int i = blockIdx.x * 256 + threadIdx.x;
  if (i >= n4) return;
  floatx4 v = ((const floatx4*)in)[i];
  ushort4v o;
  o[0] = f2b(v[0]); o[1] = f2b(v[1]); o[2] = f2b(v[2]); o[3] = f2b(v[3]);
  ((ushort4v*)out)[i] = o;
}

// ---------------------------------------------------------------------------
// GEMM: C[M,N] = A[M,K] @ B[N,K]^T   (A,B bf16 row-major K-contiguous)
//
// 256xBN tile, BK=64, 8 waves (2M x 4N), 512 thr.  ONE barrier per K-tile:
// within a tile nothing writes the buffer being read (DMA targets the other
// buffer), so the only cross-wave hazards are per tile:
//   (a) all waves done reading buf X before DMA into X   -> tile-end barrier
//   (b) all DMA into Y complete before any wave reads Y  -> vmcnt(0)+barrier
// Inside the tile each wave runs a PRIVATE pipeline (no lockstep): issue
// B-frags + A-group reads, counted lgkm fences (DS completes in-order per
// wave), MFMA group g overlaps the in-flight reads of group g+1.  This lets
// the ~1600cyc LDS read drain overlap the ~1860cyc MFMA work instead of
// serializing behind per-phase barriers (round-4: 8 barriers/tile, 30% MfmaUtil).
//
// LDS swizzle (both-sides, rule 21): LDS[r][s] holds global octet s^(r&7).
// Staging pre-permutes the per-lane GLOBAL address (LDS dest stays linear);
// fragment ds_read XORs its k-octet with row&7.  Conflict-free (measured 0).
//
// MODE: 1 = fp32 out, 2 = bf16 out + fused RoPE on cols<5120.
// Grid must be (8, N/BN); block swizzle assumes gridDim.x == 8.
// ---------------------------------------------------------------------------
#define ISSUE_A(BUF, dst, g)                                                   \
    _Pragma("unroll") for (int mm = 0; mm < 2; ++mm)                           \
      _Pragma("unroll") for (int ks = 0; ks < 2; ++ks)                         \
        dst[mm][ks] = ds_read_b128v(&As[BUF][aoff[ks] + ((g) * 2 + mm) * 1024]);

#define MFMA_G(src, g)                                                         \
    _Pragma("unroll") for (int mm = 0; mm < 2; ++mm)                           \
      _Pragma("unroll") for (int n = 0; n < NF; ++n)                           \
        _Pragma("unroll") for (int ks = 0; ks < 2; ++ks)                       \
          acc[(g) * 2 + mm][n] = __builtin_amdgcn_mfma_f32_16x16x32_bf16(      \
              src[mm][ks], bfr[n][ks], acc[(g) * 2 + mm][n], 0, 0, 0);

template <int MODE, int BN>
__global__ void __launch_bounds__(512, 2)
gemm256(const unsigned short* __restrict__ A,
        const unsigned short* __restrict__ B,
        float* __restrict__ Cf,
        unsigned short* __restrict__ Cb,
        int K, int N,
        const float* __restrict__ fc,
        const float* __restrict__ fs) {
  constexpr int BM = 256, BK = 64;
  constexpr int NF  = BN / 64;   // n-frags per wave
  constexpr int WNC = BN / 4;    // per-wave col span
  constexpr int NB  = BN / 64;   // B staging instrs per wave (8 rows each)

  __shared__ __align__(16) unsigned short As[2][BM * BK];   // 64 KiB
  __shared__ __align__(16) unsigned short Bs[2][BN * BK];   // 32/48 KiB

  const int tid  = threadIdx.x;
  const int wave = tid >> 6, lane = tid & 63;
  const int quad = lane >> 4, l15 = lane & 15;
  const int wr = wave >> 2, wc = wave & 3;

  int flat = blockIdx.y * 8 + blockIdx.x;
  const int cpx = (int)(gridDim.x * gridDim.y) >> 3;
  flat = (flat & 7) * cpx + (flat >> 3);
  const int m0 = (flat & 7) * BM;
  const int n0 = (flat >> 3) * BN;

  const int srow = lane >> 3;            // row within 8-row block
  const int soct = (lane & 7) ^ srow;    // global octet for this lane's slot
  const unsigned short* pa[4];
  const unsigned short* pb[NB];
#pragma unroll
  for (int i = 0; i < 4; ++i)
    pa[i] = A + (size_t)(m0 + wave * 32 + i * 8 + srow) * K + soct * 8;
#pragma unroll
  for (int i = 0; i < NB; ++i)
    pb[i] = B + (size_t)(n0 + wave * (BN / 8) + i * 8 + srow) * K + soct * 8;

  const int xr = l15 & 7;
  int aoff[2], boff[2];
#pragma unroll
  for (int ks = 0; ks < 2; ++ks) {
    const int sl = ((ks * 4 + quad) ^ xr) * 8;
    aoff[ks] = (wr * 128 + l15) * 64 + sl;
    boff[ks] = (wc * WNC + l15) * 64 + sl;
  }

  floatx4 acc[8][NF] = {};
  const int NT = K >> 6;

  // prologue: stage tile 0 into buffer 0, publish
#pragma unroll
  for (int i = 0; i < 4; ++i)
    gld_lds16(pa[i], &As[0][(wave * 32 + i * 8) * 64]);
#pragma unroll
  for (int i = 0; i < NB; ++i)
    gld_lds16(pb[i], &Bs[0][(wave * (BN / 8) + i * 8) * 64]);
  asm volatile("s_waitcnt vmcnt(0)" ::: "memory");
  __builtin_amdgcn_s_barrier();
  __builtin_amdgcn_sched_barrier(0);

  int t = 0, kt = 0;

#define TILE_STEP(BUF)                                                         \
  do {                                                                         \
    short8 bfr[NF][2], a0[2][2], a1[2][2], a2[2][2], a3[2][2];                 \
    _Pragma("unroll") for (int n = 0; n < NF; ++n)                             \
      _Pragma("unroll") for (int ks = 0; ks < 2; ++ks)                         \
        bfr[n][ks] = ds_read_b128v(&Bs[BUF][boff[ks] + n * 1024]);             \
    ISSUE_A(BUF, a0, 0);                                                       \
    ISSUE_A(BUF, a1, 1);                                                       \
    if (t + 1 < NT) {                                                          \
      const int kn = kt + 64;                                                  \
      _Pragma("unroll") for (int i = 0; i < 4; ++i)                            \
        gld_lds16(pa[i] + kn, &As[1 - (BUF)][(wave * 32 + i * 8) * 64]);       \
      _Pragma("unroll") for (int i = 0; i < NB; ++i)                           \
        gld_lds16(pb[i] + kn, &Bs[1 - (BUF)][(wave * (BN / 8) + i * 8) * 64]); \
    }                                                                          \
    LGKM_FENCE(4);   /* in-order DS: B-frags + a0 complete (a1 pending) */     \
    __builtin_amdgcn_s_setprio(1);                                             \
    MFMA_G(a0, 0);                                                             \
    __builtin_amdgcn_s_setprio(0);                                             \
    ISSUE_A(BUF, a2, 2);                                                       \
    LGKM_FENCE(4);   /* a1 complete (a2 pending) */                            \
    __builtin_amdgcn_s_setprio(1);                                             \
    MFMA_G(a1, 1);                                                             \
    __builtin_amdgcn_s_setprio(0);                                             \
    ISSUE_A(BUF, a3, 3);                                                       \
    LGKM_FENCE(4);   /* a2 complete (a3 pending) */                            \
    __builtin_amdgcn_s_setprio(1);                                             \
    MFMA_G(a2, 2);                                                             \
    __builtin_amdgcn_s_setprio(0);                                             \
    LGKM_FENCE(0);   /* a3 complete */                                         \
    __builtin_amdgcn_s_setprio(1);                                             \
    MFMA_G(a3, 3);                                                             \
    __builtin_amdgcn_s_setprio(0);                                             \
    asm volatile("s_waitcnt vmcnt(0)" ::: "memory");  /* own DMA (t+1) done */ \
    __builtin_amdgcn_s_barrier();    /* all DMA done; all reads of BUF done */ \
    __builtin_amdgcn_sched_barrier(0);                                         \
    kt += 64;                                                                  \
    ++t;                                                                       \
  } while (0)

  while (t < NT) {
    TILE_STEP(0);
    TILE_STEP(1);
  }
#undef TILE_STEP

  // ---- epilogue: C/D layout col = lane&15, row = quad*4 + reg ----
#pragma unroll
  for (int mi = 0; mi < 8; ++mi) {
#pragma unroll
    for (int n = 0; n < NF; ++n) {
      const int colb = n0 + wc * WNC + n * 16;   // wave-uniform
      const int col  = colb + l15;
      const bool rope = (MODE == 2) && (colb < 5120);
      const int pp = (col & 127) >> 1;
      const float sgn = (l15 & 1) ? 1.f : -1.f;
#pragma unroll
      for (int r = 0; r < 4; ++r) {
        const int row = m0 + wr * 128 + mi * 16 + quad * 4 + r;
        float v = acc[mi][n][r];
        if (rope) {
          const float partner = __shfl_xor(v, 1);
          const float c  = fc[row * 64 + pp];
          const float sn = fs[row * 64 + pp];
          v = v * c + partner * sn * sgn;
        }
        if (MODE == 1) Cf[(size_t)row * N + col] = v;
        else           Cb[(size_t)row * N + col] = f2b(v);
      }
    }
  }
}

// ---------------------------------------------------------------------------
// bf16 tiled transpose
// ---------------------------------------------------------------------------
__global__ void __launch_bounds__(256) transpose_bf16(const unsigned short* __restrict__ in,
                                                      unsigned short* __restrict__ out,
                                                      int R, int C, int in_stride) {
  __shared__ __align__(16) unsigned short tile[64][72];
  const int br = blockIdx.y * 64;
  const int bc = blockIdx.x * 64;
  const int tid = threadIdx.x;
  const int lr = tid >> 3;
  const int lc = (tid & 7) * 8;
#pragma unroll
  for (int it = 0; it < 2; ++it) {
    const int r = it * 32 + lr;
    *(short8*)&tile[r][lc] = *(const short8*)(in + (size_t)(br + r) * in_stride + bc + lc);
  }
  __syncthreads();
#pragma unroll
  for (int it = 0; it < 2; ++it) {
    const int c = it * 32 + lr;
    short8 v;
#pragma unroll
    for (int j = 0; j < 8; ++j) v[j] = (short)tile[lc + j][c];
    *(short8*)(out + (size_t)(bc + c) * R + br + lc) = v;
  }
}

// ---------------------------------------------------------------------------
// Flash attention v2 (causal, GQA 4:1). S=2048, D=128, 32 heads.
// 64-row q-tiles; block handles the PAIR (bx, 31-bx) -> exactly 33 k-tiles.
// 4 waves x 16 q-rows.  Double-buffered K/V, COALESCED staging:
//   K LDS [key 64][d-oct ^ (key&7)]  (instr = 4 rows x 256B contiguous)
//   V LDS [d 128][key-oct ^ (d&7)]   (instr = 8 rows x 128B contiguous)
// (both-sides swizzle, rule 21).  All k-loop LDS ops inline asm + counted
// lgkm fences; tile-top = vmcnt(0) + raw s_barrier.  Prefetch after softmax.
// UNCHANGED this round (verified round 4).
// ---------------------------------------------------------------------------
#define SL2E 0.1275500406721347f   /* (1/sqrt(128)) * log2(e) */

__global__ void __launch_bounds__(256) flash_attn(const unsigned short* __restrict__ Q,  // (2048,6144)
                                                  const unsigned short* __restrict__ Kp, // (2048,6144)+off
                                                  const unsigned short* __restrict__ Vt, // (1024,2048)
                                                  unsigned short* __restrict__ O) {      // (2048,4096)
  constexpr int QS = 6144;
  const int bx  = blockIdx.x;      // 0..15 -> tiles bx and 31-bx
  const int h   = blockIdx.y;
  const int kvh = h >> 2;
  const int tid = threadIdx.x;
  const int wave = tid >> 6, lane = tid & 63;
  const int quad = lane >> 4, l15 = lane & 15;
  const int xr8 = l15 & 7;

  __shared__ __align__(16) unsigned short Ks[2][8192];   // [key 64][128 d swz]
  __shared__ __align__(16) unsigned short Vs[2][8192];   // [d 128][64 key swz]
  __shared__ __align__(16) unsigned short Ps[4][16 * 88];
  unsigned short* Pw = Ps[wave];

  // ---- coalesced staging sources (pre-swizzled global octet) ----
  const unsigned short* kp4[4];   // instr ii: keys k0..k0+3, k0 = wave*16+ii*4
  const unsigned short* vp4[4];   // instr ii: d-rows d0..d0+7, d0 = wave*32+ii*8
#pragma unroll
  for (int ii = 0; ii < 4; ++ii) {
    const int k0   = wave * 16 + ii * 4;
    const int krow = k0 + (lane >> 4);
    const int goct = (lane & 15) ^ (krow & 7);
    kp4[ii] = Kp + kvh * 128 + (size_t)krow * QS + goct * 8;
    const int d0   = wave * 32 + ii * 8;
    const int drow = d0 + (lane >> 3);
    const int voct = (lane & 7) ^ ((lane >> 3) & 7);
    vp4[ii] = Vt + (size_t)(kvh * 128 + drow) * 2048 + voct * 8;
  }

  for (int seg = 0; seg < 2; ++seg) {
    const int qt  = seg ? (31 - bx) : bx;
    const int qra = qt * 64 + wave * 16;
    const int n   = qt + 1;

    short8 aq[4];
#pragma unroll
    for (int ks = 0; ks < 4; ++ks)
      aq[ks] = *(const short8*)(Q + (size_t)(qra + l15) * QS + h * 128 + ks * 32 + quad * 8);

    floatx4 oacc[8] = {};
    float mrow[4], lrow[4];
#pragma unroll
    for (int r = 0; r < 4; ++r) { mrow[r] = -1e30f; lrow[r] = 0.f; }

    // prologue: stage tile 0 -> buffer 0
#pragma unroll
    for (int ii = 0; ii < 4; ++ii) {
      gld_lds16(kp4[ii], &Ks[0][wave * 2048 + ii * 512]);
      gld_lds16(vp4[ii], &Vs[0][wave * 2048 + ii * 512]);
    }

    for (int j = 0; j < n; ++j) {
      // publish staged tile: per-wave DMA drain, raw barrier (no lgkm drain)
      asm volatile("s_waitcnt vmcnt(0)" ::: "memory");
      __builtin_amdgcn_s_barrier();
      __builtin_amdgcn_sched_barrier(0);
      const unsigned short* kb = Ks[j & 1];
      const unsigned short* vb = Vs[j & 1];
      const int c0 = j * 64;

      // ---- QK^T: 2-deep pipelined asm ds_reads + MFMA ----
      floatx4 sacc[4] = {};
      {
        short8 bkA[4], bkB[4];
#pragma unroll
        for (int tn = 0; tn < 4; ++tn)
          bkA[tn] = ds_read_b128v(&kb[(tn * 16 + l15) * 128 + ((quad ^ xr8) * 8)]);
#pragma unroll
        for (int tn = 0; tn < 4; ++tn)
          bkB[tn] = ds_read_b128v(&kb[(tn * 16 + l15) * 128 + (((4 + quad) ^ xr8) * 8)]);
        LGKM_FENCE(4);
        __builtin_amdgcn_s_setprio(1);
#pragma unroll
        for (int tn = 0; tn < 4; ++tn)
          sacc[tn] = __builtin_amdgcn_mfma_f32_16x16x32_bf16(aq[0], bkA[tn], sacc[tn], 0, 0, 0);
        __builtin_amdgcn_s_setprio(0);
#pragma unroll
        for (int tn = 0; tn < 4; ++tn)
          bkA[tn] = ds_read_b128v(&kb[(tn * 16 + l15) * 128 + (((8 + quad) ^ xr8) * 8)]);
        LGKM_FENCE(4);
        __builtin_amdgcn_s_setprio(1);
#pragma unroll
        for (int tn = 0; tn < 4; ++tn)
          sacc[tn] = __builtin_amdgcn_mfma_f32_16x16x32_bf16(aq[1], bkB[tn], sacc[tn], 0, 0, 0);
        __builtin_amdgcn_s_setprio(0);
#pragma unroll
        for (int tn = 0; tn < 4; ++tn)
          bkB[tn] = ds_read_b128v(&kb[(tn * 16 + l15) * 128 + (((12 + quad) ^ xr8) * 8)]);
        LGKM_FENCE(4);
        __builtin_amdgcn_s_setprio(1);
#pragma unroll
        for (int tn = 0; tn < 4; ++tn)
          sacc[tn] = __builtin_amdgcn_mfma_f32_16x16x32_bf16(aq[2], bkA[tn], sacc[tn], 0, 0, 0);
        __builtin_amdgcn_s_setprio(0);
        LGKM_FENCE(0);
        __builtin_amdgcn_s_setprio(1);
#pragma unroll
        for (int tn = 0; tn < 4; ++tn)
          sacc[tn] = __builtin_amdgcn_mfma_f32_16x16x32_bf16(aq[3], bkB[tn], sacc[tn], 0, 0, 0);
        __builtin_amdgcn_s_setprio(0);
      }

      // ---- online softmax (no outstanding DMA here -> shuffles are clean) ----
      const bool needmask = (c0 + 63 > qra);
#pragma unroll
      for (int r = 0; r < 4; ++r) {
        const int rowg = qra + quad * 4 + r;
        float t0 = sacc[0][r] * SL2E, t1 = sacc[1][r] * SL2E;
        float t2 = sacc[2][r] * SL2E, t3 = sacc[3][r] * SL2E;
        if (needmask) {
          t0 = (c0 +  0 + l15 <= rowg) ? t0 : -1e30f;
          t1 = (c0 + 16 + l15 <= rowg) ? t1 : -1e30f;
          t2 = (c0 + 32 + l15 <= rowg) ? t2 : -1e30f;
          t3 = (c0 + 48 + l15 <= rowg) ? t3 : -1e30f;
        }
        float mx = fmaxf(fmaxf(t0, t1), fmaxf(t2, t3));
#pragma unroll
        for (int off = 1; off < 16; off <<= 1)
          mx = fmaxf(mx, __shfl_xor(mx, off, 16));
        const float mold = mrow[r];
        const float mn   = fmaxf(mold, mx);
        const float alpha = exp2f(mold - mn);
        float p0 = exp2f(t0 - mn), p1 = exp2f(t1 - mn);
        float p2 = exp2f(t2 - mn), p3 = exp2f(t3 - mn);
        sacc[0][r] = p0; sacc[1][r] = p1; sacc[2][r] = p2; sacc[3][r] = p3;
        float lsum = (p0 + p1) + (p2 + p3);
#pragma unroll
        for (int off = 1; off < 16; off <<= 1)
          lsum += __shfl_xor(lsum, off, 16);
        mrow[r] = mn;
        lrow[r] = lrow[r] * alpha + lsum;
#pragma unroll
        for (int tn = 0; tn < 8; ++tn) oacc[tn][r] *= alpha;
      }

      // ---- prefetch next tile (latency covered by P-write + PV) ----
      if (j + 1 < n) {
        const int cc = (j + 1) * 64;
        const int nb = (j + 1) & 1;
#pragma unroll
        for (int ii = 0; ii < 4; ++ii) {
          gld_lds16(kp4[ii] + (size_t)cc * QS, &Ks[nb][wave * 2048 + ii * 512]);
          gld_lds16(vp4[ii] + cc, &Vs[nb][wave * 2048 + ii * 512]);
        }
      }

      // ---- P -> LDS (bf16, asm), transpose read, PV ----
#pragma unroll
      for (int tn = 0; tn < 4; ++tn)
#pragma unroll
        for (int r = 0; r < 4; ++r)
          ds_write_b16v(&Pw[(quad * 4 + r) * 88 + tn * 16 + l15], f2b(sacc[tn][r]));
      short8 ap0 = ds_read_b128v(&Pw[l15 * 88 + quad * 8]);
      short8 ap1 = ds_read_b128v(&Pw[l15 * 88 + 32 + quad * 8]);
      short8 bv0[8], bv1[8];
#pragma unroll
      for (int tn = 0; tn < 8; ++tn)
        bv0[tn] = ds_read_b128v(&vb[(tn * 16 + l15) * 64 + ((quad ^ xr8) * 8)]);
#pragma unroll
      for (int tn = 0; tn < 8; ++tn)
        bv1[tn] = ds_read_b128v(&vb[(tn * 16 + l15) * 64 + (((4 + quad) ^ xr8) * 8)]);
      LGKM_FENCE(8);   // in-order: P-writes, ap0/ap1, bv0 complete; bv1 pending
      __builtin_amdgcn_s_setprio(1);
#pragma unroll
      for (int tn = 0; tn < 8; ++tn)
        oacc[tn] = __builtin_amdgcn_mfma_f32_16x16x32_bf16(ap0, bv0[tn], oacc[tn], 0, 0, 0);
      __builtin_amdgcn_s_setprio(0);
      LGKM_FENCE(0);
      __builtin_amdgcn_s_setprio(1);
#pragma unroll
      for (int tn = 0; tn < 8; ++tn)
        oacc[tn] = __builtin_amdgcn_mfma_f32_16x16x32_bf16(ap1, bv1[tn], oacc[tn], 0, 0, 0);
      __builtin_amdgcn_s_setprio(0);
    }

#pragma unroll
    for (int r = 0; r < 4; ++r) {
      const float inv = 1.f / lrow[r];
      const int rowg = qra + quad * 4 + r;
#pragma unroll
      for (int tn = 0; tn < 8; ++tn)
        O[(size_t)rowg * 4096 + h * 128 + tn * 16 + l15] = f2b(oacc[tn][r] * inv);
    }
    __syncthreads();   // full drain: safe buffer reuse across segs
  }
}

// ---------------------------------------------------------------------------
// Host launcher
// ---------------------------------------------------------------------------
extern "C" void kernel_launch(void* const* d_in, const int* in_sizes, int n_in,
                              void* d_out, int out_size, void* d_ws, size_t ws_size,
                              hipStream_t stream) {
  const float* x  = (const float*)d_in[0];
  const float* wq = (const float*)d_in[1];
  const float* wk = (const float*)d_in[2];
  const float* wv = (const float*)d_in[3];
  const float* wo = (const float*)d_in[4];
  const float* fc = (const float*)d_in[7];
  const float* fs = (const float*)d_in[8];
  float* out = (float*)d_out;

  char* ws = (char*)d_ws;
  unsigned short* xb    = (unsigned short*)(ws + 0);          // x bf16       16 MB
  unsigned short* wqkvb = (unsigned short*)(ws + 16777216);   // wq|wk|wv     48 MB
  unsigned short* wob   = (unsigned short*)(ws + 67108864);   // wo bf16      32 MB
  unsigned short* qkv   = (unsigned short*)(ws + 100663296);  // (2048,6144)  24 MB
  unsigned short* vt    = (unsigned short*)(ws + 125829120);  // (1024,2048)   4 MB
  unsigned short* ob    = (unsigned short*)(ws + 130023424);  // (2048,4096)  16 MB
  unsigned short* wkb = wqkvb + (size_t)4096 * 4096;
  unsigned short* wvb = wkb + (size_t)1024 * 4096;

  f2b_kernel<<<8192,  256, 0, stream>>>(x,  xb,    2097152);
  f2b_kernel<<<16384, 256, 0, stream>>>(wq, wqkvb, 4194304);
  f2b_kernel<<<4096,  256, 0, stream>>>(wk, wkb,   1048576);
  f2b_kernel<<<4096,  256, 0, stream>>>(wv, wvb,   1048576);
  f2b_kernel<<<16384, 256, 0, stream>>>(wo, wob,   4194304);

  // QKV projection with fused RoPE on Q|K columns: (2048,6144) = xb @ wqkv^T
  gemm256<2, 192><<<dim3(8, 32), 512, 0, stream>>>(xb, wqkvb, nullptr, qkv,
                                                   4096, 6144, fc, fs);

  // V^T: (2048,1024) slice at col 5120 -> (1024,2048)
  transpose_bf16<<<dim3(16, 32), 256, 0, stream>>>(qkv + 5120, vt, 2048, 1024, 6144);

  // flash attention -> O (2048,4096) bf16
  flash_attn<<<dim3(16, 32), 256, 0, stream>>>(qkv, qkv + 4096, vt, ob);

  // output projection: O @ wo^T -> fp32 d_out
  gemm256<1, 128><<<dim3(8, 32), 512, 0, stream>>>(ob, wob, out, nullptr,
                                                   4096, 4096, nullptr, nullptr);
}